// Round 4
// baseline (393.759 us; speedup 1.0000x reference)
//
#include <hip/hip_runtime.h>

#define N_NODES 50000
#define N_EDGES 800000
#define NPAD 50176   // 49 * 1024, padded histogram size

typedef float f32x4 __attribute__((ext_vector_type(4)));
typedef short bf16x8 __attribute__((ext_vector_type(8)));

__device__ __forceinline__ float fast_tanh(float x) {
  // exact algebra: tanh(x) = 1 - 2/(exp(2x)+1)
  float e = __expf(2.0f * x);
  return 1.0f - 2.0f / (e + 1.0f);
}

__device__ __forceinline__ unsigned short f2bf_rne(float x) {
  unsigned u = __float_as_uint(x);
  unsigned r = u + 0x7FFFu + ((u >> 16) & 1u);
  return (unsigned short)(r >> 16);
}

// ---------- prep1: W12 = pi_W1 @ pi_W2  [128x64]; b12 = pi_b1 @ pi_W2 + pi_b2 [64]
__global__ __launch_bounds__(256) void prep1_kernel(
    const float* __restrict__ piW1, const float* __restrict__ pib1,
    const float* __restrict__ piW2, const float* __restrict__ pib2,
    float* __restrict__ W12, float* __restrict__ b12) {
  int gid = blockIdx.x * 256 + threadIdx.x;
  if (gid < 128 * 64) {
    int m = gid >> 6, c = gid & 63;
    float acc = 0.f;
    #pragma unroll 8
    for (int k = 0; k < 64; ++k) acc = fmaf(piW1[m * 64 + k], piW2[k * 64 + c], acc);
    W12[gid] = acc;
  } else if (gid < 128 * 64 + 64) {
    int c = gid - 128 * 64;
    float acc = pib2[c];
    for (int k = 0; k < 64; ++k) acc = fmaf(pib1[k], piW2[k * 64 + c], acc);
    b12[c] = acc;
  }
}

// ---------- prep_b: Bpack[ks][ct][lane][j] = bf16( W3i[kidx][col] )
// W3i[kidx][c] = sum_m piW3[k][m*8+b]*iiW1[m][c], kidx=k*8+b
__global__ __launch_bounds__(256) void prep_b_kernel(
    const float* __restrict__ piW3, const float* __restrict__ iiW1,
    unsigned short* __restrict__ Bpack) {
  int gid = blockIdx.x * 256 + threadIdx.x;  // 32768 total
  int j = gid & 7;
  int lane = (gid >> 3) & 63;
  int ct = (gid >> 9) & 3;
  int ks = gid >> 11;
  int kidx = ks * 32 + ((lane >> 4) << 3) + j;
  int col = ct * 16 + (lane & 15);
  int k = kidx >> 3, b = kidx & 7;
  float acc = 0.f;
  #pragma unroll 8
  for (int mm = 0; mm < 64; ++mm)
    acc = fmaf(piW3[k * 512 + mm * 8 + b], iiW1[mm * 64 + col], acc);
  Bpack[gid] = f2bf_rne(acc);
}

// ---------- prep_w2: W2pack[ks][ct][lane][j] = bf16( iiW2[kidx][col] )
__global__ __launch_bounds__(256) void prep_w2_kernel(
    const float* __restrict__ iiW2, unsigned short* __restrict__ W2pack) {
  int gid = blockIdx.x * 256 + threadIdx.x;  // 4096 total
  int j = gid & 7;
  int lane = (gid >> 3) & 63;
  int ct = (gid >> 9) & 3;
  int ks = gid >> 11;
  int kidx = ks * 32 + ((lane >> 4) << 3) + j;
  int col = ct * 16 + (lane & 15);
  W2pack[gid] = f2bf_rne(iiW2[kidx * 64 + col]);
}

// ---------- sort step 1: histogram of idx_j
__global__ __launch_bounds__(256) void hist_kernel(
    const int* __restrict__ idx_j, int* __restrict__ counts) {
  int e = blockIdx.x * 256 + threadIdx.x;
  if (e < N_EDGES) atomicAdd(&counts[idx_j[e]], 1);
}

// ---------- sort step 2: exclusive scan of counts (single block, 49 chunks of 1024)
__global__ __launch_bounds__(1024) void scan_kernel(
    const int* __restrict__ counts, int* __restrict__ offsets,
    int* __restrict__ cursors) {
  __shared__ int buf[1024];
  int tid = threadIdx.x;
  int base = 0;
  for (int c = 0; c < NPAD / 1024; ++c) {
    int idx = c * 1024 + tid;
    int v = counts[idx];
    buf[tid] = v;
    __syncthreads();
    for (int off = 1; off < 1024; off <<= 1) {
      int t = (tid >= off) ? buf[tid - off] : 0;
      __syncthreads();
      buf[tid] += t;
      __syncthreads();
    }
    int excl = buf[tid] - v;
    offsets[idx] = base + excl;
    cursors[idx] = base + excl;
    base += buf[1023];
    __syncthreads();
  }
}

// ---------- sort step 3: scatter edges into j-sorted order
__global__ __launch_bounds__(256) void sort_scatter_kernel(
    const int* __restrict__ idx_i, const int* __restrict__ idx_j,
    int* __restrict__ cursors,
    int* __restrict__ sorted_i, int* __restrict__ sorted_j,
    int* __restrict__ sorted_e) {
  int e = blockIdx.x * 256 + threadIdx.x;
  if (e < N_EDGES) {
    int j = idx_j[e];
    int pos = atomicAdd(&cursors[j], 1);
    sorted_i[pos] = idx_i[e];
    sorted_j[pos] = j;
    sorted_e[pos] = e;
  }
}

// ---------- node: p1 = tanh(p@ppW1+b1)@ppW2+b2 ; qa = p1@W12[0:64]; qb = p1@W12[64:128]
__global__ __launch_bounds__(256) void node_kernel(
    const float* __restrict__ p,
    const float* __restrict__ ppW1, const float* __restrict__ ppb1,
    const float* __restrict__ ppW2, const float* __restrict__ ppb2,
    const float* __restrict__ W12,
    float* __restrict__ qa, float* __restrict__ qb) {
  __shared__ float sW1[64 * 64];
  __shared__ float sW2[64 * 64];
  __shared__ float sW12[128 * 64];
  __shared__ float sb1[64], sb2[64];
  __shared__ float sX[4][8][64];
  int tid = threadIdx.x;
  for (int i = tid; i < 64 * 64; i += 256) { sW1[i] = ppW1[i]; sW2[i] = ppW2[i]; }
  for (int i = tid; i < 128 * 64; i += 256) sW12[i] = W12[i];
  if (tid < 64) { sb1[tid] = ppb1[tid]; sb2[tid] = ppb2[tid]; }
  __syncthreads();
  int wave = tid >> 6, lane = tid & 63;
  int rowbase = blockIdx.x * 32 + wave * 8;

  float4* sXf4 = (float4*)&sX[wave][0][0];
  for (int t = lane; t < 128; t += 64) {
    int r = t >> 4, c4 = t & 15;
    int row = rowbase + r;
    float4 v = make_float4(0.f, 0.f, 0.f, 0.f);
    if (row < N_NODES) v = ((const float4*)p)[row * 16 + c4];
    sXf4[t] = v;
  }
  __syncthreads();

  float h[8];
  #pragma unroll
  for (int r = 0; r < 8; ++r) h[r] = sb1[lane];
  for (int k = 0; k < 64; ++k) {
    float w = sW1[k * 64 + lane];
    #pragma unroll
    for (int r = 0; r < 8; ++r) h[r] = fmaf(sX[wave][r][k], w, h[r]);
  }
  #pragma unroll
  for (int r = 0; r < 8; ++r) h[r] = fast_tanh(h[r]);
  __syncthreads();
  #pragma unroll
  for (int r = 0; r < 8; ++r) sX[wave][r][lane] = h[r];
  __syncthreads();

  float g[8];
  #pragma unroll
  for (int r = 0; r < 8; ++r) g[r] = sb2[lane];
  for (int k = 0; k < 64; ++k) {
    float w = sW2[k * 64 + lane];
    #pragma unroll
    for (int r = 0; r < 8; ++r) g[r] = fmaf(sX[wave][r][k], w, g[r]);
  }
  __syncthreads();
  #pragma unroll
  for (int r = 0; r < 8; ++r) sX[wave][r][lane] = g[r];
  __syncthreads();

  float a[8], b[8];
  #pragma unroll
  for (int r = 0; r < 8; ++r) { a[r] = 0.f; b[r] = 0.f; }
  for (int k = 0; k < 64; ++k) {
    float wa = sW12[k * 64 + lane];
    float wb = sW12[(64 + k) * 64 + lane];
    #pragma unroll
    for (int r = 0; r < 8; ++r) {
      float x = sX[wave][r][k];
      a[r] = fmaf(x, wa, a[r]);
      b[r] = fmaf(x, wb, b[r]);
    }
  }
  #pragma unroll
  for (int r = 0; r < 8; ++r) {
    int row = rowbase + r;
    if (row < N_NODES) {
      qa[row * 64 + lane] = a[r];
      qb[row * 64 + lane] = b[r];
    }
  }
}

// ---------- edge (j-sorted): h2 = qa[i]+qb[j]+b12 ; s = (h2 (x) basis) @ W3i + ii_b1 (MFMA)
//            t = tanh(s) ; i2 = t @ ii_W2 + ii_b2 (MFMA) ; run-aggregated atomic scatter
// 1024 threads = 16 waves, 256 edges/block. LDS union 64KB:
//   phase0 = h2 tile [256][64] f32 XOR-swizzled ; phase1 = Bpack (64KB)
//   phase2 = t tile [256][72] bf16 ; phase3 = i2 half-tile [128][68] f32
__global__ __launch_bounds__(1024, 8) void edge_kernel(
    const int* __restrict__ sorted_i, const int* __restrict__ sorted_j,
    const int* __restrict__ sorted_e,
    const float* __restrict__ basis,
    const float* __restrict__ qa, const float* __restrict__ qb,
    const float* __restrict__ b12,
    const unsigned short* __restrict__ Bpack,
    const unsigned short* __restrict__ W2pack,
    const float* __restrict__ iib1, const float* __restrict__ iib2,
    float* __restrict__ out) {
  __shared__ __align__(16) unsigned short sB[32768];  // 64 KB
  float* sH2 = (float*)sB;
  unsigned short* sT = sB;
  float* sF = (float*)sB;

  int tid = threadIdx.x;
  int e0 = blockIdx.x * 256;

  // ---- phase 0: gather h2 into LDS (f32, swizzled). qb rows are L1-hot (sorted j).
  for (int t = tid; t < 4096; t += 1024) {
    int e = t >> 4, q = t & 15;
    int ii = sorted_i[e0 + e];
    int jj = sorted_j[e0 + e];
    float4 va = ((const float4*)qa)[ii * 16 + q];
    float4 vb = ((const float4*)qb)[jj * 16 + q];
    float4 vc = ((const float4*)b12)[q];
    float4 h;
    h.x = va.x + vb.x + vc.x;
    h.y = va.y + vb.y + vc.y;
    h.z = va.z + vb.z + vc.z;
    h.w = va.w + vb.w + vc.w;
    int dw = e * 64 + ((q * 4) ^ ((e & 7) << 3));  // XOR keeps 16B alignment
    *((float4*)(sH2 + dw)) = h;
  }
  __syncthreads();

  int w = tid >> 6, l = tid & 63;
  int m = l & 15, s = l >> 4;
  int eloc = w * 16 + m;        // this lane's edge row (A-operand row = l&15)
  int swz = (eloc & 7) << 3;

  // per-lane A inputs: h2[e][k] for k = 4*ks + s, and basis[orig_e][0..8)
  float h2r[16];
  #pragma unroll
  for (int t = 0; t < 16; ++t) h2r[t] = sH2[eloc * 64 + ((t * 4 + s) ^ swz)];

  float bas[8];
  {
    int eorig = sorted_e[e0 + eloc];
    const float4* bp = (const float4*)(basis + (size_t)eorig * 8);
    float4 b0 = bp[0], b1 = bp[1];
    bas[0] = b0.x; bas[1] = b0.y; bas[2] = b0.z; bas[3] = b0.w;
    bas[4] = b1.x; bas[5] = b1.y; bas[6] = b1.z; bas[7] = b1.w;
  }
  __syncthreads();

  // ---- phase 1: stage Bpack (64 KB) into LDS
  {
    const uint4* g = (const uint4*)Bpack;
    uint4* d = (uint4*)sB;
    #pragma unroll
    for (int t = 0; t < 4; ++t) d[tid + t * 1024] = g[tid + t * 1024];
  }
  __syncthreads();

  // C init with ii_b1 (col = ct*16 + m)
  f32x4 c0, c1, c2, c3;
  {
    float v0 = iib1[m], v1 = iib1[16 + m], v2 = iib1[32 + m], v3 = iib1[48 + m];
    c0 = (f32x4){v0, v0, v0, v0};
    c1 = (f32x4){v1, v1, v1, v1};
    c2 = (f32x4){v2, v2, v2, v2};
    c3 = (f32x4){v3, v3, v3, v3};
  }

  // ---- main K-loop: 16 K-steps x 4 col-tiles, rne-bf16 A = 64 MFMA/wave
  const bf16x8* Bl = (const bf16x8*)sB;
  #pragma unroll
  for (int ks = 0; ks < 16; ++ks) {
    bf16x8 B0 = Bl[(ks * 4 + 0) * 64 + l];
    bf16x8 B1 = Bl[(ks * 4 + 1) * 64 + l];
    bf16x8 B2 = Bl[(ks * 4 + 2) * 64 + l];
    bf16x8 B3 = Bl[(ks * 4 + 3) * 64 + l];
    float hv = h2r[ks];
    union { unsigned u[4]; bf16x8 v; } A;
    #pragma unroll
    for (int j = 0; j < 4; ++j) {
      float p0 = hv * bas[2 * j];
      float p1 = hv * bas[2 * j + 1];
      asm("v_cvt_pk_bf16_f32 %0, %1, %2" : "=v"(A.u[j]) : "v"(p0), "v"(p1));
    }
    c0 = __builtin_amdgcn_mfma_f32_16x16x32_bf16(A.v, B0, c0, 0, 0, 0);
    c1 = __builtin_amdgcn_mfma_f32_16x16x32_bf16(A.v, B1, c1, 0, 0, 0);
    c2 = __builtin_amdgcn_mfma_f32_16x16x32_bf16(A.v, B2, c2, 0, 0, 0);
    c3 = __builtin_amdgcn_mfma_f32_16x16x32_bf16(A.v, B3, c3, 0, 0, 0);
  }
  __syncthreads();  // all waves done reading Bpack region

  // ---- phase 2: tanh -> t tile (bf16). C/D layout: col = ct*16+m, row(local) = s*4+r
  #pragma unroll
  for (int r = 0; r < 4; ++r) {
    int row = w * 16 + s * 4 + r;
    sT[row * 72 + 0 * 16 + m] = f2bf_rne(fast_tanh(c0[r]));
    sT[row * 72 + 1 * 16 + m] = f2bf_rne(fast_tanh(c1[r]));
    sT[row * 72 + 2 * 16 + m] = f2bf_rne(fast_tanh(c2[r]));
    sT[row * 72 + 3 * 16 + m] = f2bf_rne(fast_tanh(c3[r]));
  }
  __syncthreads();

  // ---- second GEMM: i2 = t @ ii_W2 + ii_b2   (K=64: 2 K-steps x 4 col-tiles)
  f32x4 d0, d1, d2, d3;
  {
    float v0 = iib2[m], v1 = iib2[16 + m], v2 = iib2[32 + m], v3 = iib2[48 + m];
    d0 = (f32x4){v0, v0, v0, v0};
    d1 = (f32x4){v1, v1, v1, v1};
    d2 = (f32x4){v2, v2, v2, v2};
    d3 = (f32x4){v3, v3, v3, v3};
  }
  const bf16x8* Wl = (const bf16x8*)W2pack;
  #pragma unroll
  for (int ks = 0; ks < 2; ++ks) {
    bf16x8 Af = *(const bf16x8*)(sT + eloc * 72 + ks * 32 + s * 8);
    d0 = __builtin_amdgcn_mfma_f32_16x16x32_bf16(Af, Wl[(ks * 4 + 0) * 64 + l], d0, 0, 0, 0);
    d1 = __builtin_amdgcn_mfma_f32_16x16x32_bf16(Af, Wl[(ks * 4 + 1) * 64 + l], d1, 0, 0, 0);
    d2 = __builtin_amdgcn_mfma_f32_16x16x32_bf16(Af, Wl[(ks * 4 + 2) * 64 + l], d2, 0, 0, 0);
    d3 = __builtin_amdgcn_mfma_f32_16x16x32_bf16(Af, Wl[(ks * 4 + 3) * 64 + l], d3, 0, 0, 0);
  }

  // ---- phase 3: run-aggregated scatter. Two halves of 128 edges through LDS (f32),
  //      then each wave walks 8 consecutive sorted edges as full 64-col rows,
  //      accumulating while j is unchanged; one whole-row atomic per run.
  #pragma unroll
  for (int h = 0; h < 2; ++h) {
    __syncthreads();
    if ((w >> 3) == h) {
      int wl = w & 7;
      #pragma unroll
      for (int r = 0; r < 4; ++r) {
        int row = wl * 16 + s * 4 + r;
        sF[row * 68 + 0  + m] = d0[r];
        sF[row * 68 + 16 + m] = d1[r];
        sF[row * 68 + 32 + m] = d2[r];
        sF[row * 68 + 48 + m] = d3[r];
      }
    }
    __syncthreads();
    {
      int base_e = e0 + h * 128 + w * 8;
      float acc = sF[(w * 8) * 68 + l];
      int cur_j = sorted_j[base_e];
      #pragma unroll
      for (int rr = 1; rr < 8; ++rr) {
        int nj = sorted_j[base_e + rr];
        float v = sF[(w * 8 + rr) * 68 + l];
        if (nj == cur_j) {
          acc += v;
        } else {
          atomicAdd(&out[(size_t)cur_j * 64 + l], acc);
          acc = v;
          cur_j = nj;
        }
      }
      atomicAdd(&out[(size_t)cur_j * 64 + l], acc);
    }
  }
}

extern "C" void kernel_launch(void* const* d_in, const int* in_sizes, int n_in,
                              void* d_out, int out_size, void* d_ws, size_t ws_size,
                              hipStream_t stream) {
  const float* p     = (const float*)d_in[0];
  const int*   idx_i = (const int*)d_in[1];
  const int*   idx_j = (const int*)d_in[2];
  const float* basis = (const float*)d_in[3];
  const float* ppW1  = (const float*)d_in[4];
  const float* ppb1  = (const float*)d_in[5];
  const float* ppW2  = (const float*)d_in[6];
  const float* ppb2  = (const float*)d_in[7];
  const float* piW1  = (const float*)d_in[8];
  const float* pib1  = (const float*)d_in[9];
  const float* piW2  = (const float*)d_in[10];
  const float* pib2  = (const float*)d_in[11];
  const float* piW3  = (const float*)d_in[12];
  const float* iiW1  = (const float*)d_in[13];
  const float* iib1  = (const float*)d_in[14];
  const float* iiW2  = (const float*)d_in[15];
  const float* iib2  = (const float*)d_in[16];

  float* ws  = (float*)d_ws;
  float* qa  = ws;                         // 3,200,000 f
  float* qb  = ws + 3200000;               // 3,200,000 f
  float* W12 = ws + 6400000;               // 8192 f
  float* b12 = ws + 6408192;               // 64 f
  unsigned short* Bpack  = (unsigned short*)(ws + 6408256);   // 32768 bf16 (16384 f)
  unsigned short* W2pack = (unsigned short*)(ws + 6424640);   // 4096 bf16 (2048 f)
  int* counts   = (int*)(ws + 6426688);    // NPAD ints
  int* offsets  = (int*)(ws + 6476864);    // NPAD ints
  int* cursors  = (int*)(ws + 6527040);    // NPAD ints
  int* sorted_i = (int*)(ws + 6577216);    // 800000 ints
  int* sorted_j = (int*)(ws + 7377216);    // 800000 ints
  int* sorted_e = (int*)(ws + 8177216);    // 800000 ints  (end ~35.9 MB)

  hipMemsetAsync(d_out, 0, (size_t)out_size * sizeof(float), stream);
  hipMemsetAsync(counts, 0, (size_t)NPAD * sizeof(int), stream);
  prep1_kernel<<<33, 256, 0, stream>>>(piW1, pib1, piW2, pib2, W12, b12);
  prep_b_kernel<<<128, 256, 0, stream>>>(piW3, iiW1, Bpack);
  prep_w2_kernel<<<16, 256, 0, stream>>>(iiW2, W2pack);
  hist_kernel<<<3125, 256, 0, stream>>>(idx_j, counts);
  scan_kernel<<<1, 1024, 0, stream>>>(counts, offsets, cursors);
  sort_scatter_kernel<<<3125, 256, 0, stream>>>(idx_i, idx_j, cursors,
                                                sorted_i, sorted_j, sorted_e);
  node_kernel<<<1563, 256, 0, stream>>>(p, ppW1, ppb1, ppW2, ppb2, W12, qa, qb);
  edge_kernel<<<3125, 1024, 0, stream>>>(sorted_i, sorted_j, sorted_e, basis,
                                         qa, qb, b12, Bpack, W2pack,
                                         iib1, iib2, (float*)d_out);
}

// Round 5
// 303.109 us; speedup vs baseline: 1.2991x; 1.2991x over previous
//
#include <hip/hip_runtime.h>

#define N_NODES 50000
#define N_EDGES 800000
#define NPAD 50176   // 49 * 1024, padded histogram size

typedef float f32x4 __attribute__((ext_vector_type(4)));
typedef short bf16x8 __attribute__((ext_vector_type(8)));

__device__ __forceinline__ float fast_tanh(float x) {
  // tanh(x) = 1 - 2/(exp(2x)+1); v_rcp_f32 (1 ulp) instead of IEEE div sequence
  float e = __expf(2.0f * x);
  float r;
  asm("v_rcp_f32 %0, %1" : "=v"(r) : "v"(e + 1.0f));
  return fmaf(-2.0f, r, 1.0f);
}

__device__ __forceinline__ unsigned short f2bf_rne(float x) {
  unsigned u = __float_as_uint(x);
  unsigned r = u + 0x7FFFu + ((u >> 16) & 1u);
  return (unsigned short)(r >> 16);
}

// ---------- fused prep: [0,32768) Bpack ; [32768,40960) W12 ; [40960,41024) b12 ;
//                        [41024,45120) W2pack
// Bpack[ks][ct][lane][j] = bf16( W3i[kidx][col] ), W3i[kidx][c]=sum_m piW3[k][m*8+b]*iiW1[m][c]
// W12 = pi_W1 @ pi_W2 ; b12 = pi_b1 @ pi_W2 + pi_b2 ; W2pack same packing of iiW2
__global__ __launch_bounds__(256) void prep_all_kernel(
    const float* __restrict__ piW1, const float* __restrict__ pib1,
    const float* __restrict__ piW2, const float* __restrict__ pib2,
    const float* __restrict__ piW3, const float* __restrict__ iiW1,
    const float* __restrict__ iiW2,
    float* __restrict__ W12, float* __restrict__ b12,
    unsigned short* __restrict__ Bpack, unsigned short* __restrict__ W2pack) {
  int gid = blockIdx.x * 256 + threadIdx.x;
  if (gid < 32768) {
    int j = gid & 7;
    int lane = (gid >> 3) & 63;
    int ct = (gid >> 9) & 3;
    int ks = gid >> 11;
    int kidx = ks * 32 + ((lane >> 4) << 3) + j;
    int col = ct * 16 + (lane & 15);
    int k = kidx >> 3, b = kidx & 7;
    float acc = 0.f;
    #pragma unroll 8
    for (int mm = 0; mm < 64; ++mm)
      acc = fmaf(piW3[k * 512 + mm * 8 + b], iiW1[mm * 64 + col], acc);
    Bpack[gid] = f2bf_rne(acc);
  } else if (gid < 41024) {
    int g1 = gid - 32768;
    if (g1 < 8192) {
      int m = g1 >> 6, c = g1 & 63;
      float acc = 0.f;
      #pragma unroll 8
      for (int k = 0; k < 64; ++k) acc = fmaf(piW1[m * 64 + k], piW2[k * 64 + c], acc);
      W12[g1] = acc;
    } else {
      int c = g1 - 8192;
      float acc = pib2[c];
      for (int k = 0; k < 64; ++k) acc = fmaf(pib1[k], piW2[k * 64 + c], acc);
      b12[c] = acc;
    }
  } else if (gid < 45120) {
    int g2 = gid - 41024;
    int j = g2 & 7;
    int lane = (g2 >> 3) & 63;
    int ct = (g2 >> 9) & 3;
    int ks = g2 >> 11;
    int kidx = ks * 32 + ((lane >> 4) << 3) + j;
    int col = ct * 16 + (lane & 15);
    W2pack[g2] = f2bf_rne(iiW2[kidx * 64 + col]);
  }
}

// ---------- sort step 1: histogram of idx_j
__global__ __launch_bounds__(256) void hist_kernel(
    const int* __restrict__ idx_j, int* __restrict__ counts) {
  int e = blockIdx.x * 256 + threadIdx.x;
  if (e < N_EDGES) atomicAdd(&counts[idx_j[e]], 1);
}

// ---------- sort step 2a: per-chunk exclusive scan (49 blocks x 1024)
__global__ __launch_bounds__(1024) void scanA_kernel(
    const int* __restrict__ counts, int* __restrict__ cursors,
    int* __restrict__ blocksums) {
  __shared__ int buf[1024];
  int b = blockIdx.x, tid = threadIdx.x;
  int idx = b * 1024 + tid;
  int v = counts[idx];
  buf[tid] = v;
  __syncthreads();
  for (int off = 1; off < 1024; off <<= 1) {
    int t = (tid >= off) ? buf[tid - off] : 0;
    __syncthreads();
    buf[tid] += t;
    __syncthreads();
  }
  cursors[idx] = buf[tid] - v;
  if (tid == 1023) blocksums[b] = buf[1023];
}

// ---------- sort step 2b: add scanned chunk bases (each block scans 49 sums in LDS)
__global__ __launch_bounds__(1024) void scanC_kernel(
    int* __restrict__ cursors, const int* __restrict__ blocksums) {
  __shared__ int sb[49];
  __shared__ int sbase;
  int b = blockIdx.x, tid = threadIdx.x;
  if (tid < 49) sb[tid] = blocksums[tid];
  __syncthreads();
  if (tid == 0) {
    int acc = 0;
    for (int i = 0; i < b; ++i) acc += sb[i];
    sbase = acc;
  }
  __syncthreads();
  cursors[b * 1024 + tid] += sbase;
}

// ---------- sort step 3: scatter edges into j-sorted order
__global__ __launch_bounds__(256) void sort_scatter_kernel(
    const int* __restrict__ idx_i, const int* __restrict__ idx_j,
    int* __restrict__ cursors,
    int2* __restrict__ sorted_ij, int* __restrict__ sorted_e) {
  int e = blockIdx.x * 256 + threadIdx.x;
  if (e < N_EDGES) {
    int j = idx_j[e];
    int pos = atomicAdd(&cursors[j], 1);
    sorted_ij[pos] = make_int2(idx_i[e], j);
    sorted_e[pos] = e;
  }
}

// ---------- node: p1 = tanh(p@ppW1+b1)@ppW2+b2 ; qa = p1@W12[0:64]; qb = p1@W12[64:128]
__global__ __launch_bounds__(256) void node_kernel(
    const float* __restrict__ p,
    const float* __restrict__ ppW1, const float* __restrict__ ppb1,
    const float* __restrict__ ppW2, const float* __restrict__ ppb2,
    const float* __restrict__ W12,
    float* __restrict__ qa, float* __restrict__ qb) {
  __shared__ float sW1[64 * 64];
  __shared__ float sW2[64 * 64];
  __shared__ float sW12[128 * 64];
  __shared__ float sb1[64], sb2[64];
  __shared__ float sX[4][8][64];
  int tid = threadIdx.x;
  for (int i = tid; i < 64 * 64; i += 256) { sW1[i] = ppW1[i]; sW2[i] = ppW2[i]; }
  for (int i = tid; i < 128 * 64; i += 256) sW12[i] = W12[i];
  if (tid < 64) { sb1[tid] = ppb1[tid]; sb2[tid] = ppb2[tid]; }
  __syncthreads();
  int wave = tid >> 6, lane = tid & 63;
  int rowbase = blockIdx.x * 32 + wave * 8;

  float4* sXf4 = (float4*)&sX[wave][0][0];
  for (int t = lane; t < 128; t += 64) {
    int r = t >> 4, c4 = t & 15;
    int row = rowbase + r;
    float4 v = make_float4(0.f, 0.f, 0.f, 0.f);
    if (row < N_NODES) v = ((const float4*)p)[row * 16 + c4];
    sXf4[t] = v;
  }
  __syncthreads();

  float h[8];
  #pragma unroll
  for (int r = 0; r < 8; ++r) h[r] = sb1[lane];
  for (int k = 0; k < 64; ++k) {
    float w = sW1[k * 64 + lane];
    #pragma unroll
    for (int r = 0; r < 8; ++r) h[r] = fmaf(sX[wave][r][k], w, h[r]);
  }
  #pragma unroll
  for (int r = 0; r < 8; ++r) h[r] = fast_tanh(h[r]);
  __syncthreads();
  #pragma unroll
  for (int r = 0; r < 8; ++r) sX[wave][r][lane] = h[r];
  __syncthreads();

  float g[8];
  #pragma unroll
  for (int r = 0; r < 8; ++r) g[r] = sb2[lane];
  for (int k = 0; k < 64; ++k) {
    float w = sW2[k * 64 + lane];
    #pragma unroll
    for (int r = 0; r < 8; ++r) g[r] = fmaf(sX[wave][r][k], w, g[r]);
  }
  __syncthreads();
  #pragma unroll
  for (int r = 0; r < 8; ++r) sX[wave][r][lane] = g[r];
  __syncthreads();

  float a[8], b[8];
  #pragma unroll
  for (int r = 0; r < 8; ++r) { a[r] = 0.f; b[r] = 0.f; }
  for (int k = 0; k < 64; ++k) {
    float wa = sW12[k * 64 + lane];
    float wb = sW12[(64 + k) * 64 + lane];
    #pragma unroll
    for (int r = 0; r < 8; ++r) {
      float x = sX[wave][r][k];
      a[r] = fmaf(x, wa, a[r]);
      b[r] = fmaf(x, wb, b[r]);
    }
  }
  #pragma unroll
  for (int r = 0; r < 8; ++r) {
    int row = rowbase + r;
    if (row < N_NODES) {
      qa[row * 64 + lane] = a[r];
      qb[row * 64 + lane] = b[r];
    }
  }
}

// ---------- edge (j-sorted): h2 = qa[i]+qb[j]+b12 ; s = (h2 (x) basis) @ W3i + ii_b1 (MFMA)
//            t = tanh(s) ; i2 = t @ ii_W2 + ii_b2 (MFMA) ; run-aggregated atomic scatter
__global__ __launch_bounds__(1024, 8) void edge_kernel(
    const int2* __restrict__ sorted_ij, const int* __restrict__ sorted_e,
    const float* __restrict__ basis,
    const float* __restrict__ qa, const float* __restrict__ qb,
    const float* __restrict__ b12,
    const unsigned short* __restrict__ Bpack,
    const unsigned short* __restrict__ W2pack,
    const float* __restrict__ iib1, const float* __restrict__ iib2,
    float* __restrict__ out) {
  __shared__ __align__(16) unsigned short sB[32768];  // 64 KB
  float* sH2 = (float*)sB;
  unsigned short* sT = sB;
  float* sF = (float*)sB;

  int tid = threadIdx.x;
  int e0 = blockIdx.x * 256;

  // ---- phase 0: gather h2 into LDS (f32, swizzled). qb rows are L1-hot (sorted j).
  for (int t = tid; t < 4096; t += 1024) {
    int e = t >> 4, q = t & 15;
    int2 se = sorted_ij[e0 + e];
    float4 va = ((const float4*)qa)[se.x * 16 + q];
    float4 vb = ((const float4*)qb)[se.y * 16 + q];
    float4 vc = ((const float4*)b12)[q];
    float4 h;
    h.x = va.x + vb.x + vc.x;
    h.y = va.y + vb.y + vc.y;
    h.z = va.z + vb.z + vc.z;
    h.w = va.w + vb.w + vc.w;
    int dw = e * 64 + ((q * 4) ^ ((e & 7) << 3));  // XOR keeps 16B alignment
    *((float4*)(sH2 + dw)) = h;
  }
  __syncthreads();

  int w = tid >> 6, l = tid & 63;
  int m = l & 15, s = l >> 4;
  int eloc = w * 16 + m;        // this lane's edge row (A-operand row = l&15)
  int swz = (eloc & 7) << 3;

  // per-lane A inputs: h2[e][k] for k = 4*ks + s, and basis[orig_e][0..8)
  float h2r[16];
  #pragma unroll
  for (int t = 0; t < 16; ++t) h2r[t] = sH2[eloc * 64 + ((t * 4 + s) ^ swz)];

  float bas[8];
  {
    int eorig = sorted_e[e0 + eloc];
    const float4* bp = (const float4*)(basis + (size_t)eorig * 8);
    float4 b0 = bp[0], b1 = bp[1];
    bas[0] = b0.x; bas[1] = b0.y; bas[2] = b0.z; bas[3] = b0.w;
    bas[4] = b1.x; bas[5] = b1.y; bas[6] = b1.z; bas[7] = b1.w;
  }
  __syncthreads();

  // ---- phase 1: stage Bpack (64 KB) into LDS
  {
    const uint4* g = (const uint4*)Bpack;
    uint4* d = (uint4*)sB;
    #pragma unroll
    for (int t = 0; t < 4; ++t) d[tid + t * 1024] = g[tid + t * 1024];
  }
  __syncthreads();

  // C init with ii_b1 (col = ct*16 + m)
  f32x4 c0, c1, c2, c3;
  {
    float v0 = iib1[m], v1 = iib1[16 + m], v2 = iib1[32 + m], v3 = iib1[48 + m];
    c0 = (f32x4){v0, v0, v0, v0};
    c1 = (f32x4){v1, v1, v1, v1};
    c2 = (f32x4){v2, v2, v2, v2};
    c3 = (f32x4){v3, v3, v3, v3};
  }

  // ---- main K-loop: 16 K-steps x 4 col-tiles, rne-bf16 A = 64 MFMA/wave
  const bf16x8* Bl = (const bf16x8*)sB;
  #pragma unroll
  for (int ks = 0; ks < 16; ++ks) {
    bf16x8 B0 = Bl[(ks * 4 + 0) * 64 + l];
    bf16x8 B1 = Bl[(ks * 4 + 1) * 64 + l];
    bf16x8 B2 = Bl[(ks * 4 + 2) * 64 + l];
    bf16x8 B3 = Bl[(ks * 4 + 3) * 64 + l];
    float hv = h2r[ks];
    union { unsigned u[4]; bf16x8 v; } A;
    #pragma unroll
    for (int j = 0; j < 4; ++j) {
      float p0 = hv * bas[2 * j];
      float p1 = hv * bas[2 * j + 1];
      asm("v_cvt_pk_bf16_f32 %0, %1, %2" : "=v"(A.u[j]) : "v"(p0), "v"(p1));
    }
    c0 = __builtin_amdgcn_mfma_f32_16x16x32_bf16(A.v, B0, c0, 0, 0, 0);
    c1 = __builtin_amdgcn_mfma_f32_16x16x32_bf16(A.v, B1, c1, 0, 0, 0);
    c2 = __builtin_amdgcn_mfma_f32_16x16x32_bf16(A.v, B2, c2, 0, 0, 0);
    c3 = __builtin_amdgcn_mfma_f32_16x16x32_bf16(A.v, B3, c3, 0, 0, 0);
  }
  __syncthreads();  // all waves done reading Bpack region

  // ---- phase 2: tanh -> t tile (bf16). C/D layout: col = ct*16+m, row(local) = s*4+r
  #pragma unroll
  for (int r = 0; r < 4; ++r) {
    int row = w * 16 + s * 4 + r;
    sT[row * 72 + 0 * 16 + m] = f2bf_rne(fast_tanh(c0[r]));
    sT[row * 72 + 1 * 16 + m] = f2bf_rne(fast_tanh(c1[r]));
    sT[row * 72 + 2 * 16 + m] = f2bf_rne(fast_tanh(c2[r]));
    sT[row * 72 + 3 * 16 + m] = f2bf_rne(fast_tanh(c3[r]));
  }
  __syncthreads();

  // ---- second GEMM: i2 = t @ ii_W2 + ii_b2   (K=64: 2 K-steps x 4 col-tiles)
  f32x4 d0, d1, d2, d3;
  {
    float v0 = iib2[m], v1 = iib2[16 + m], v2 = iib2[32 + m], v3 = iib2[48 + m];
    d0 = (f32x4){v0, v0, v0, v0};
    d1 = (f32x4){v1, v1, v1, v1};
    d2 = (f32x4){v2, v2, v2, v2};
    d3 = (f32x4){v3, v3, v3, v3};
  }
  const bf16x8* Wl = (const bf16x8*)W2pack;
  #pragma unroll
  for (int ks = 0; ks < 2; ++ks) {
    bf16x8 Af = *(const bf16x8*)(sT + eloc * 72 + ks * 32 + s * 8);
    d0 = __builtin_amdgcn_mfma_f32_16x16x32_bf16(Af, Wl[(ks * 4 + 0) * 64 + l], d0, 0, 0, 0);
    d1 = __builtin_amdgcn_mfma_f32_16x16x32_bf16(Af, Wl[(ks * 4 + 1) * 64 + l], d1, 0, 0, 0);
    d2 = __builtin_amdgcn_mfma_f32_16x16x32_bf16(Af, Wl[(ks * 4 + 2) * 64 + l], d2, 0, 0, 0);
    d3 = __builtin_amdgcn_mfma_f32_16x16x32_bf16(Af, Wl[(ks * 4 + 3) * 64 + l], d3, 0, 0, 0);
  }

  // ---- phase 3: run-aggregated scatter (two 128-edge halves through LDS)
  #pragma unroll
  for (int h = 0; h < 2; ++h) {
    __syncthreads();
    if ((w >> 3) == h) {
      int wl = w & 7;
      #pragma unroll
      for (int r = 0; r < 4; ++r) {
        int row = wl * 16 + s * 4 + r;
        sF[row * 68 + 0  + m] = d0[r];
        sF[row * 68 + 16 + m] = d1[r];
        sF[row * 68 + 32 + m] = d2[r];
        sF[row * 68 + 48 + m] = d3[r];
      }
    }
    __syncthreads();
    {
      int base_e = e0 + h * 128 + w * 8;
      float acc = sF[(w * 8) * 68 + l];
      int cur_j = sorted_ij[base_e].y;
      #pragma unroll
      for (int rr = 1; rr < 8; ++rr) {
        int nj = sorted_ij[base_e + rr].y;
        float v = sF[(w * 8 + rr) * 68 + l];
        if (nj == cur_j) {
          acc += v;
        } else {
          atomicAdd(&out[(size_t)cur_j * 64 + l], acc);
          acc = v;
          cur_j = nj;
        }
      }
      atomicAdd(&out[(size_t)cur_j * 64 + l], acc);
    }
  }
}

extern "C" void kernel_launch(void* const* d_in, const int* in_sizes, int n_in,
                              void* d_out, int out_size, void* d_ws, size_t ws_size,
                              hipStream_t stream) {
  const float* p     = (const float*)d_in[0];
  const int*   idx_i = (const int*)d_in[1];
  const int*   idx_j = (const int*)d_in[2];
  const float* basis = (const float*)d_in[3];
  const float* ppW1  = (const float*)d_in[4];
  const float* ppb1  = (const float*)d_in[5];
  const float* ppW2  = (const float*)d_in[6];
  const float* ppb2  = (const float*)d_in[7];
  const float* piW1  = (const float*)d_in[8];
  const float* pib1  = (const float*)d_in[9];
  const float* piW2  = (const float*)d_in[10];
  const float* pib2  = (const float*)d_in[11];
  const float* piW3  = (const float*)d_in[12];
  const float* iiW1  = (const float*)d_in[13];
  const float* iib1  = (const float*)d_in[14];
  const float* iiW2  = (const float*)d_in[15];
  const float* iib2  = (const float*)d_in[16];

  float* ws  = (float*)d_ws;
  float* qa  = ws;                         // 3,200,000 f
  float* qb  = ws + 3200000;               // 3,200,000 f
  float* W12 = ws + 6400000;               // 8192 f
  float* b12 = ws + 6408192;               // 64 f
  unsigned short* Bpack  = (unsigned short*)(ws + 6408256);   // 32768 bf16 (16384 f)
  unsigned short* W2pack = (unsigned short*)(ws + 6424640);   // 4096 bf16 (2048 f)
  int* counts    = (int*)(ws + 6426688);   // NPAD ints
  int* cursors   = (int*)(ws + 6476864);   // NPAD ints
  int* blocksums = (int*)(ws + 6527040);   // 64 ints
  int2* sorted_ij = (int2*)(ws + 6527104); // 800000 int2 (1.6M f, 8B-aligned)
  int* sorted_e   = (int*)(ws + 8127104);  // 800000 ints (end ~35.7 MB)

  hipMemsetAsync(d_out, 0, (size_t)out_size * sizeof(float), stream);
  hipMemsetAsync(counts, 0, (size_t)NPAD * sizeof(int), stream);
  prep_all_kernel<<<177, 256, 0, stream>>>(piW1, pib1, piW2, pib2, piW3, iiW1, iiW2,
                                           W12, b12, Bpack, W2pack);
  hist_kernel<<<3125, 256, 0, stream>>>(idx_j, counts);
  scanA_kernel<<<49, 1024, 0, stream>>>(counts, cursors, blocksums);
  scanC_kernel<<<49, 1024, 0, stream>>>(cursors, blocksums);
  sort_scatter_kernel<<<3125, 256, 0, stream>>>(idx_i, idx_j, cursors,
                                                sorted_ij, sorted_e);
  node_kernel<<<1563, 256, 0, stream>>>(p, ppW1, ppb1, ppW2, ppb2, W12, qa, qb);
  edge_kernel<<<3125, 1024, 0, stream>>>(sorted_ij, sorted_e, basis,
                                         qa, qb, b12, Bpack, W2pack,
                                         iib1, iib2, (float*)d_out);
}